// Round 4
// baseline (354.648 us; speedup 1.0000x reference)
//
#include <hip/hip_runtime.h>

// ---------------------------------------------------------------------------
// QuaternionLinear == one GEMM: out[M=32768][N=1024] = x[M][K=1024] * W^T + b
// where W[4o+co][4i+ci] = sign(co,ci) * weight_{comp(co,ci)}[o][i].
// Round 3: fuse the fp32->bf16 conversion of x INTO the GEMM A-staging
// (float4 global loads -> RNE cvt in VGPRs -> ds_write_b64), deleting the
// standalone cvt pass. B stays on the global_load_lds width=16 path from the
// precomputed combined bf16 W. Grid is n-inner so A re-reads are L3-adjacent.
// ---------------------------------------------------------------------------

typedef __attribute__((ext_vector_type(8))) short bf16x8;   // 8 bf16 = 4 VGPRs
typedef __attribute__((ext_vector_type(4))) float f32x4;

#define M_TOT 32768
#define N_TOT 1024
#define K_TOT 1024
#define BM 128
#define BN 128
#define BK 32

__device__ __forceinline__ unsigned short f2bf(float f) {
    union { float f; unsigned int u; } v; v.f = f;
    unsigned int u = v.u;
    u += 0x7fffu + ((u >> 16) & 1u);   // round-to-nearest-even
    return (unsigned short)(u >> 16);
}

// ---- kernel 1: combined quaternion weight matrix, bf16, [N][K] (B^T) ------
// One block per output row n: co = n&3 is block-uniform -> scalar branch.
//   co=0: [ r, -i, -j, -k]   co=1: [ i,  r,  k, -j]
//   co=2: [ j, -k,  r,  i]   co=3: [ k,  j, -i,  r]
__global__ __launch_bounds__(256) void build_w(const float* __restrict__ R,
                                               const float* __restrict__ I,
                                               const float* __restrict__ J,
                                               const float* __restrict__ Kw,
                                               ushort4* __restrict__ Wb) {
    int n = blockIdx.x;          // 0..1023 (output row of W)
    int i = threadIdx.x;         // 0..255  (input quaternion index)
    int o = n >> 2, co = n & 3;
    int base = o * 256 + i;
    float r = R[base], ii = I[base], j = J[base], k = Kw[base];
    float v0, v1, v2, v3;
    if (co == 0)      { v0 = r;  v1 = -ii; v2 = -j;  v3 = -k; }
    else if (co == 1) { v0 = ii; v1 = r;   v2 = k;   v3 = -j; }
    else if (co == 2) { v0 = j;  v1 = -k;  v2 = r;   v3 = ii; }
    else              { v0 = k;  v1 = j;   v2 = -ii; v3 = r;  }
    ushort4 w;
    w.x = f2bf(v0); w.y = f2bf(v1); w.z = f2bf(v2); w.w = f2bf(v3);
    Wb[n * 256 + i] = w;         // coalesced 8B/lane
}

// ---- kernel 2: fused cvt+GEMM, fp32 A x bf16 W^T -> fp32 C + bias ---------
__device__ __forceinline__ void async_lds16(const void* g, void* l) {
    __builtin_amdgcn_global_load_lds(
        (const __attribute__((address_space(1))) unsigned int*)g,
        (__attribute__((address_space(3))) unsigned int*)l,
        16, 0, 0);
}

__global__ __launch_bounds__(256) void gemm_fused(
        const float* __restrict__ A,            // [M][K] fp32 (x)
        const unsigned short* __restrict__ B,   // [N][K] bf16 (combined W)
        const float* __restrict__ bias,         // [N]
        float* __restrict__ C) {                // [M][N] fp32
    __shared__ unsigned short As[BM * BK];      // row-major [128][32], 8 KiB
    __shared__ unsigned short Bs[BN * BK];      // row-major [128][32], 8 KiB

    const int tid  = threadIdx.x;
    const int wave = tid >> 6;
    const int lane = tid & 63;
    const int quad = lane >> 4;     // 0..3
    const int r16  = lane & 15;     // 0..15
    const int wm   = wave & 1;      // wave grid 2x2, each wave 64x64
    const int wn   = wave >> 1;

    // n-inner grid: blockIdx.x = n-tile (8), blockIdx.y = m-tile (256).
    // Consecutive blocks share the same A stripe -> A re-reads are L3-local.
    const int n0 = blockIdx.x * BN;
    const int m0 = blockIdx.y * BM;

    f32x4 acc[4][4];
#pragma unroll
    for (int i = 0; i < 4; ++i)
#pragma unroll
        for (int j = 0; j < 4; ++j)
            acc[i][j] = (f32x4){0.f, 0.f, 0.f, 0.f};

    // B staging geometry (global_load_lds): one wave inst = 64 lanes x 16 B
    // = 16 rows x 32 bf16; LDS dest is wave-uniform base + lane*16.
    const int srow = lane >> 2;          // 0..15 within a 16-row chunk
    const int scol = (lane & 3) * 8;     // bf16 column

    // A staging geometry (VGPR cvt path): per k-step the tile is 128 rows x
    // 32 fp32 = 1024 float4; thread covers 4: chunk c -> idx = c*256+tid,
    // row = idx>>3, colq = idx&7 (8 consecutive lanes = 128 B of one row).
    const int arow0 = tid >> 3;          // rows arow0 + 32*c
    const int acol  = (tid & 7) * 4;     // fp32 column

    for (int k0 = 0; k0 < K_TOT; k0 += BK) {
        // A fp32 loads: no LDS hazard -> issue before the barrier so they
        // overlap the previous iteration's MFMA tail.
        float4 av[4];
#pragma unroll
        for (int c = 0; c < 4; ++c)
            av[c] = *(const float4*)(A + (size_t)(m0 + arow0 + c * 32) * K_TOT
                                       + k0 + acol);

        __syncthreads();                 // LDS reuse from previous iter

#pragma unroll
        for (int j = 0; j < 2; ++j) {    // B: async global->LDS, 16B/lane
            int q   = wave * 2 + j;      // chunk 0..7
            int row = q * 16 + srow;
            async_lds16(B + (size_t)(n0 + row) * K_TOT + k0 + scol, Bs + q * 512);
        }

        // convert + stage A (waits av via vmcnt; B-lds stays in flight)
#pragma unroll
        for (int c = 0; c < 4; ++c) {
            ushort4 uv;
            uv.x = f2bf(av[c].x); uv.y = f2bf(av[c].y);
            uv.z = f2bf(av[c].z); uv.w = f2bf(av[c].w);
            *(ushort4*)(As + (arow0 + c * 32) * BK + acol) = uv;  // ds_write_b64
        }

        __syncthreads();                 // drains vmcnt+lgkm: tiles visible

        bf16x8 af[4], bf[4];
#pragma unroll
        for (int i = 0; i < 4; ++i) {
            // A-operand layout: A[m = lane&15][k = quad*8 + j]
            af[i] = *(const bf16x8*)(As + (wm * 64 + i * 16 + r16) * BK + quad * 8);
            bf[i] = *(const bf16x8*)(Bs + (wn * 64 + i * 16 + r16) * BK + quad * 8);
        }
#pragma unroll
        for (int i = 0; i < 4; ++i)
#pragma unroll
            for (int j = 0; j < 4; ++j)
                acc[i][j] = __builtin_amdgcn_mfma_f32_16x16x32_bf16(
                    af[i], bf[j], acc[i][j], 0, 0, 0);
    }

    // epilogue: C/D layout col = lane&15 (N), row = quad*4 + reg (M)
#pragma unroll
    for (int j = 0; j < 4; ++j) {
        int col  = n0 + wn * 64 + j * 16 + r16;
        float bv = bias[col];
#pragma unroll
        for (int i = 0; i < 4; ++i) {
            int rowb = m0 + wm * 64 + i * 16 + quad * 4;
            f32x4 v  = acc[i][j];
#pragma unroll
            for (int r = 0; r < 4; ++r)
                C[(size_t)(rowb + r) * N_TOT + col] = v[r] + bv;
        }
    }
}

extern "C" void kernel_launch(void* const* d_in, const int* in_sizes, int n_in,
                              void* d_out, int out_size, void* d_ws, size_t ws_size,
                              hipStream_t stream) {
    const float* x    = (const float*)d_in[0];   // [4, 8192, 1024]
    const float* rw   = (const float*)d_in[1];   // [256, 256]
    const float* iw   = (const float*)d_in[2];
    const float* jw   = (const float*)d_in[3];
    const float* kw   = (const float*)d_in[4];
    const float* bias = (const float*)d_in[5];   // [1024]
    float* out = (float*)d_out;                  // [4, 8192, 1024]

    // workspace: combined W in bf16 at offset 0 (2 MiB)
    unsigned short* Wb = (unsigned short*)d_ws;

    // 1) build combined 1024x1024 bf16 weight (B^T layout), 1 block/row
    build_w<<<N_TOT, 256, 0, stream>>>(rw, iw, jw, kw, (ushort4*)Wb);

    // 2) fused cvt+GEMM: grid n-inner (8) x m-tiles (256)
    dim3 grid(N_TOT / BN, M_TOT / BM);
    gemm_fused<<<grid, 256, 0, stream>>>(x, Wb, bias, out);
}